// Round 3
// baseline (942.141 us; speedup 1.0000x reference)
//
#include <hip/hip_runtime.h>
#include <math.h>

#define W    3072
#define HH   3072
#define HOUT 3060       // HH - 12 (valid conv output for 13x13 kernel)
#define TW   64         // output cols per block
#define TH   56         // output rows per block (4 waves x 14 rows)
#define XR   68         // xt rows = TH + 12
#define XTS  76         // xt col stride (even -> b64-aligned col-pair reads)
#define VTS  77         // vt col stride (odd -> scalar reads/writes conflict-free)
#define VTW  (14*VTS)   // per-wave vt words = 1078
#define GX   48
#define GY   55
#define GZ   2
#define NTHR (GX*GY*GZ*256)

typedef float f2 __attribute__((ext_vector_type(2)));

// pair tables: p[j] = {tap[j], tap[j-1]} (0-padded) so one packed FMA updates
// output cols (2jj, 2jj+1); per-output accumulation order identical to scalar.
struct HessTaps {
  f2 pa[14], pbb[14], pm[14], pn[14];   // H-pass pair tables
  float a[13], bb[13], m[13], n[13];    // V-pass scalar taps
};

__device__ __forceinline__ f2 pk_fma(f2 a, f2 b, f2 c) {
#if defined(__has_builtin) && __has_builtin(__builtin_elementwise_fma)
  return __builtin_elementwise_fma(a, b, c);   // -> v_pk_fma_f32
#else
  f2 r; r.x = fmaf(a.x, b.x, c.x); r.y = fmaf(a.y, b.y, c.y); return r;
#endif
}

// per-wave shuffle reduce -> one f64 atomic per wave (no barriers, no LDS)
__device__ __forceinline__ void wave_red_atomic(float v, double* a) {
  #pragma unroll
  for (int o = 32; o > 0; o >>= 1) v += __shfl_down(v, o, 64);
  if ((threadIdx.x & 63) == 0) unsafeAtomicAdd(a, (double)v);
}

// ---- Hessian + TV + folded gf/mse, both images via gridDim.z ---------------
// 64x56 output tile, 4 waves x 14 rows, wave-local V->H, ONE barrier total.
// Latency plan:
//  * xv[26] (f2 col-pair regs) batch-read from xt once; V1 from regs.
//  * T window batch-read from GLOBAL into tr[26] after H1; xv -= tr in regs
//    (replaces the d-update phase: no mid-kernel re-staging, no barriers).
//  * V2/V3 reuse xv regs -> V-pass LDS reads 3x26 -> 1x26 b64 per wave.
//  * gf/mse operands preloaded right after the subtract (tr regs dead) and
//    consumed at the end -> streaming tail hides under V2..H3 compute.
// LDS: xt 68*76*4=20672 + vt 4*1078*4=17248 = 37920 B -> 4 blocks/CU.
__global__ __launch_bounds__(256, 4) void hess_kernel(const float* __restrict__ Gnn,
                                                      const float* __restrict__ Lr,
                                                      const float* __restrict__ T,
                                                      const float* __restrict__ Xr,
                                                      const float* __restrict__ St,
                                                      const float* __restrict__ Mp,
                                                      double* acc, HessTaps tp) {
  __shared__ float xt[XR * XTS];
  __shared__ float vt[4 * VTW];
  const float* img = (blockIdx.z == 0) ? Gnn : Lr;
  int oy = blockIdx.y * TH, ox = blockIdx.x * TW;
  int t = threadIdx.x;
  int wv = t >> 6, ln = t & 63;    // wave id 0..3, lane 0..63
  int r0 = wv * 14;

  // load xt (68 rows x 76 cols) as aligned float4 with edge masking
  for (int idx = t; idx < XR * 19; idx += 256) {
    int r = idx / 19, g = idx - r * 19;
    int gr = oy + r, gc = ox + 4 * g;
    float4 v = {0.f, 0.f, 0.f, 0.f};
    if (gr < HH) {
      const float* p = &img[(size_t)gr * W + gc];
      if (gc + 3 < W) v = *(const float4*)p;
      else {
        if (gc < W)     v.x = p[0];
        if (gc + 1 < W) v.y = p[1];
        if (gc + 2 < W) v.z = p[2];
      }
    }
    *(float4*)&xt[r * XTS + 4 * g] = v;
  }
  __syncthreads();     // the ONLY barrier

  float tvl = 0.f;   // TV accumulator
  float hl  = 0.f;   // Hessian accumulator

  // TV Dx term on x: |x(r,c) - x(r,c+1)|  (lanes contiguous -> free)
  {
    int gc = ox + ln;
    if (gc < W - 1) {
      #pragma unroll
      for (int i = 0; i < 14; ++i) {
        int r = r0 + i;
        if (oy + r < HH)
          tvl += fabsf(xt[r * XTS + ln] - xt[r * XTS + ln + 1]);
      }
    }
  }

  // batch-read the wave's 26-row col-pair window into registers (once)
  f2 xv[26];
  if (ln < 38) {
    const float* xp = &xt[r0 * XTS + 2 * ln];
    #pragma unroll
    for (int u = 0; u < 26; ++u) xv[u] = *(const f2*)(xp + u * XTS);
  }
  __builtin_amdgcn_sched_barrier(0);

  // ---- V pass from registers; writes vt (scalar, stride 77 -> conflict-free)
  #define VPASS(TAP)                                                        \
    if (ln < 38) {                                                          \
      f2 o_[14];                                                            \
      _Pragma("unroll")                                                     \
      for (int i = 0; i < 14; ++i) o_[i] = (f2){0.f, 0.f};                  \
      _Pragma("unroll")                                                     \
      for (int u = 0; u < 26; ++u) {                                        \
        _Pragma("unroll")                                                   \
        for (int i = 0; i < 14; ++i) {                                      \
          int kk = u - i;                                                   \
          if (kk >= 0 && kk <= 12) {                                        \
            float tv_ = (TAP)[kk];                                          \
            o_[i] = pk_fma((f2){tv_, tv_}, xv[u], o_[i]);                   \
          }                                                                 \
        }                                                                   \
      }                                                                     \
      float* vw = &vt[wv * VTW + 2 * ln];                                   \
      _Pragma("unroll")                                                     \
      for (int i = 0; i < 14; ++i) {                                        \
        vw[i * VTS]     = o_[i].x;                                          \
        vw[i * VTS + 1] = o_[i].y;                                          \
      }                                                                     \
    }

  // ---- H pass: scalar sliding reads of the SAME wave's vt rows (stride 77
  // -> <=2 lanes/bank); packed col-pair accumulators with pair-tap tables.
  #define HSECOND(PTAB, WGT)                                                \
    {                                                                       \
      int r14 = ln & 15, cg = ln >> 4;                                      \
      if (r14 < 14) {                                                       \
        const float* vrow = &vt[wv * VTW + r14 * VTS + cg * 16];            \
        f2 o_[8];                                                           \
        _Pragma("unroll")                                                   \
        for (int jj = 0; jj < 8; ++jj) o_[jj] = (f2){0.f, 0.f};             \
        _Pragma("unroll")                                                   \
        for (int j = 0; j < 28; ++j) {                                      \
          float v = vrow[j];                                                \
          f2 vv = {v, v};                                                   \
          _Pragma("unroll")                                                 \
          for (int jj = 0; jj < 8; ++jj) {                                  \
            int k2 = j - 2 * jj;                                            \
            if (k2 >= 0 && k2 <= 13)                                        \
              o_[jj] = pk_fma((PTAB)[k2], vv, o_[jj]);                      \
          }                                                                 \
        }                                                                   \
        int gr = oy + r0 + r14;                                             \
        int gc0 = ox + cg * 16;                                             \
        float wr = (gr < HOUT) ? (WGT) : 0.f;                               \
        _Pragma("unroll")                                                   \
        for (int jj = 0; jj < 8; ++jj) {                                    \
          float m0 = (gc0 + 2 * jj     < HOUT) ? wr : 0.f;                  \
          float m1 = (gc0 + 2 * jj + 1 < HOUT) ? wr : 0.f;                  \
          hl = fmaf(m0, fabsf(o_[jj].x), hl);                               \
          hl = fmaf(m1, fabsf(o_[jj].y), hl);                               \
        }                                                                   \
      }                                                                     \
    }

  // term 1: conv(x, Gxx) = vert bb, horiz a
  VPASS(tp.bb);
  HSECOND(tp.pa, 1.0f);

  // d = x - target, entirely in registers (batched global b64 loads)
  if (ln < 38) {
    int gc = ox + 2 * ln;
    bool cok = (gc < W);           // gc even, W even -> pair fully in or out
    const float* tb = &T[(size_t)(oy + r0) * W + gc];
    f2 tr[26];
    #pragma unroll
    for (int u = 0; u < 26; ++u) {
      f2 v = {0.f, 0.f};
      if (cok && (oy + r0 + u) < HH) v = *(const f2*)(tb + (size_t)u * W);
      tr[u] = v;
    }
    __builtin_amdgcn_sched_barrier(0);
    #pragma unroll
    for (int u = 0; u < 26; ++u) xv[u] = xv[u] - tr[u];
  }

  // TV Dy term on d from registers: |d(r,c) - d(r+1,c)|
  if (ln < 32) {                    // col-pairs 0..31 = local cols 0..63
    #pragma unroll
    for (int i = 0; i < 14; ++i) {
      if (oy + r0 + i < HH - 1) {
        f2 dd = xv[i] - xv[i + 1];
        tvl += fabsf(dd.x);
        tvl += fabsf(dd.y);
      }
    }
  }

  // preload gf/mse operands now (tr regs dead); consumed after H3
  int bid = (blockIdx.z * GY + blockIdx.y) * GX + blockIdx.x;
  int i0 = bid * 256 + t;
  int i1 = i0 + NTHR;
  const int n4 = (W * HH) / 4;
  float4 ga0 = ((const float4*)Xr)[i0];    // i0 < n4 always (NTHR < n4)
  float4 gb0 = ((const float4*)St)[i0];
  float4 ga1 = {0.f, 0.f, 0.f, 0.f}, gb1 = ga1;
  bool has1 = (i1 < n4);
  if (has1) { ga1 = ((const float4*)Xr)[i1]; gb1 = ((const float4*)St)[i1]; }
  float mT = 0.f, mG = 0.f, mM = 0.f;
  bool hasm = (i0 < 384 * 384);
  if (hasm) {
    int si = i0 / 384, sj = i0 - si * 384;
    int id = si * 8 * W + sj * 8;
    mT = T[id]; mG = Gnn[id]; mM = Mp[id];
  }
  __builtin_amdgcn_sched_barrier(0);

  // term 2: conv(d, Gyy) = vert a, horiz bb
  VPASS(tp.a);
  HSECOND(tp.pbb, 1.0f);

  // term 3: conv(d, Gxy) = vert m, horiz n, weight 2 (isotropic)
  VPASS(tp.m);
  HSECOND(tp.pn, 2.0f);

  // folded gf term (gf(x,x)==x exactly -> sum|st-x|) + sampled L1*map
  float gm = fabsf(gb0.x - ga0.x) + fabsf(gb0.y - ga0.y)
           + fabsf(gb0.z - ga0.z) + fabsf(gb0.w - ga0.w);
  if (has1)
    gm += fabsf(gb1.x - ga1.x) + fabsf(gb1.y - ga1.y)
        + fabsf(gb1.z - ga1.z) + fabsf(gb1.w - ga1.w);
  if (hasm) gm += fabsf(mT - mG) * mM;

  wave_red_atomic(tvl, &acc[1]);
  wave_red_atomic(hl,  &acc[3]);
  wave_red_atomic(gm,  &acc[0]);
}

// ---- combine ---------------------------------------------------------------
__global__ void finalize_kernel(const double* acc, float* out) {
  out[0] = (float)(acc[0] + acc[2] + 0.1 * acc[1] + 0.5 * acc[3]);
}

extern "C" void kernel_launch(void* const* d_in, const int* in_sizes, int n_in,
                              void* d_out, int out_size, void* d_ws, size_t ws_size,
                              hipStream_t stream) {
  const float* xraw = (const float*)d_in[0];   // outputGNNraw
  const float* gnn  = (const float*)d_in[1];   // outputGNN
  const float* lr   = (const float*)d_in[2];   // outputLR
  const float* st   = (const float*)d_in[3];   // smoothedTarget
  const float* tg   = (const float*)d_in[4];   // targets
  const float* mp   = (const float*)d_in[5];   // map
  float* out = (float*)d_out;

  double* acc = (double*)d_ws;
  hipMemsetAsync(d_ws, 0, 32, stream);   // zero the 4 f64 accumulators

  // separable Hessian-of-Gaussian taps (sigma=1, t = -6..6):
  //   Gxx[i,j] = bb(i)*a(j); Gyy[i,j] = a(i)*bb(j); Gxy[i,j] = m(i)*n(j)
  HessTaps tp;
  const double PI2 = 6.283185307179586476925287;
  for (int k = 0; k < 13; ++k) {
    double tt = (double)(k - 6);
    double g = exp(-0.5 * tt * tt);
    tp.a[k]  = (float)((tt * tt - 1.0) * g / PI2);
    tp.bb[k] = (float)g;
    tp.m[k]  = (float)(tt * g / PI2);
    tp.n[k]  = (float)(tt * g);
  }
  // pair tables for the packed H pass: p[j] = {tap[j], tap[j-1]}, 0-padded
  for (int j = 0; j < 14; ++j) {
    tp.pa[j]  = (f2){ (j < 13) ? tp.a[j]  : 0.f, (j >= 1) ? tp.a[j - 1]  : 0.f };
    tp.pbb[j] = (f2){ (j < 13) ? tp.bb[j] : 0.f, (j >= 1) ? tp.bb[j - 1] : 0.f };
    tp.pm[j]  = (f2){ (j < 13) ? tp.m[j]  : 0.f, (j >= 1) ? tp.m[j - 1]  : 0.f };
    tp.pn[j]  = (f2){ (j < 13) ? tp.n[j]  : 0.f, (j >= 1) ? tp.n[j - 1]  : 0.f };
  }

  // grid: 48 x-tiles * 55 y-tiles (55*56=3080 >= 3072, masked) * {GNN, LR}
  hess_kernel<<<dim3(GX, GY, GZ), 256, 0, stream>>>(gnn, lr, tg, xraw, st, mp,
                                                    acc, tp);

  finalize_kernel<<<1, 1, 0, stream>>>(acc, out);
}